// Round 1
// baseline (9803.543 us; speedup 1.0000x reference)
//
#include <hip/hip_runtime.h>
#include <math.h>

#define B_  32
#define T_  200
#define R_  512
#define F_  128
#define BR_ 4
#define C_  10
#define J_  (R_ * BR_)   // 2048
#define VTH 0.5f

// ---------------------------------------------------------------------------
// Workspace layout (floats):
//   W1   : [J_][R_]        @ 0          (1,048,576)   masked recurrent weights, input half
//   W2T  : [R_][J_]        @ 1,048,576  (1,048,576)   masked recurrent weights, spike half, TRANSPOSED
//   cur  : [B_*T_][R_]     @ 2,097,152  (3,276,800)   input currents
//   proj : [B_*T_][J_]     @ 5,373,952  (13,107,200)  precomputed input-driven projection (+b_rnn)
// total: 18,481,152 floats = 73.9 MB
// ---------------------------------------------------------------------------

// W1[j*512 + r] = w_rnn[j*1024 + r] * mask[j*1024 + r]   (first half columns)
__global__ __launch_bounds__(256) void prep_w1(const float* __restrict__ w_rnn,
                                               const float* __restrict__ mask,
                                               float* __restrict__ W1) {
    int idx = blockIdx.x * 256 + threadIdx.x;   // < 2048*512
    int j = idx >> 9;
    int r = idx & 511;
    W1[idx] = w_rnn[j * 1024 + r] * mask[j * 1024 + r];
}

// W2T[r*2048 + j] = w_rnn[j*1024 + 512 + r] * mask[...]  (second half, transposed)
__global__ __launch_bounds__(256) void prep_w2t(const float* __restrict__ w_rnn,
                                                const float* __restrict__ mask,
                                                float* __restrict__ W2T) {
    __shared__ float tile[64][65];
    int j0 = blockIdx.x * 64;   // 32 tiles over J_
    int r0 = blockIdx.y * 64;   // 8 tiles over R_
    int tx  = threadIdx.x & 63;
    int ty4 = threadIdx.x >> 6; // 0..3
    #pragma unroll
    for (int i = 0; i < 16; i++) {
        int jl = ty4 * 16 + i;
        size_t gi = (size_t)(j0 + jl) * 1024 + 512 + r0 + tx;
        tile[jl][tx] = w_rnn[gi] * mask[gi];
    }
    __syncthreads();
    #pragma unroll
    for (int i = 0; i < 16; i++) {
        int rl = ty4 * 16 + i;
        W2T[(size_t)(r0 + rl) * J_ + j0 + tx] = tile[tx][rl];
    }
}

// currents[bt*R + r] = dot(input[bt, r, :], w_in) + b_in
// One half-wave (32 lanes, float4 each) per 128-float row. 2 rows per wave.
__global__ __launch_bounds__(256) void currents_kernel(const float* __restrict__ inp,
                                                       const float* __restrict__ w_in,
                                                       const float* __restrict__ b_in,
                                                       float* __restrict__ cur) {
    int wave = (blockIdx.x * 256 + threadIdx.x) >> 6;  // 0..32767
    int lane = threadIdx.x & 63;
    int l    = lane & 31;
    int half = lane >> 5;
    float4 w4 = ((const float4*)w_in)[l];
    float bb = b_in[0];
    const float4* in4 = (const float4*)inp;
    #pragma unroll 2
    for (int i = 0; i < 50; i++) {
        size_t p   = (size_t)i * 32768 + wave;   // row pair index < 1,638,400
        size_t row = 2 * p + half;
        float4 v = in4[row * 32 + l];
        float acc = v.x * w4.x + v.y * w4.y + v.z * w4.z + v.w * w4.w;
        acc += __shfl_xor(acc, 1);
        acc += __shfl_xor(acc, 2);
        acc += __shfl_xor(acc, 4);
        acc += __shfl_xor(acc, 8);
        acc += __shfl_xor(acc, 16);
        if (l == 0) cur[row] = acc + bb;
    }
}

// proj[bt*2048 + j] = sum_r cur[bt, r] * W1[j, r] + b_rnn[j]
// M=6400 (bt), N=2048 (j), K=512. 64x64 tile, 4x4 per thread, fp32.
__global__ __launch_bounds__(256) void gemm_proj(const float* __restrict__ A,   // cur [6400x512]
                                                 const float* __restrict__ Bw,  // W1  [2048x512]
                                                 const float* __restrict__ bias,
                                                 float* __restrict__ Cc) {      // proj [6400x2048]
    __shared__ float As[16][68];
    __shared__ float Bs[16][68];
    int tid = threadIdx.x;
    int tx = tid & 15, ty = tid >> 4;
    int m0 = blockIdx.y * 64, n0 = blockIdx.x * 64;
    int lrow = tid >> 2;        // 0..63
    int lk   = (tid & 3) * 4;   // 0,4,8,12
    float acc[4][4] = {};
    for (int k0 = 0; k0 < 512; k0 += 16) {
        float4 a4 = *(const float4*)&A [(size_t)(m0 + lrow) * 512 + k0 + lk];
        float4 b4 = *(const float4*)&Bw[(size_t)(n0 + lrow) * 512 + k0 + lk];
        As[lk + 0][lrow] = a4.x; As[lk + 1][lrow] = a4.y;
        As[lk + 2][lrow] = a4.z; As[lk + 3][lrow] = a4.w;
        Bs[lk + 0][lrow] = b4.x; Bs[lk + 1][lrow] = b4.y;
        Bs[lk + 2][lrow] = b4.z; Bs[lk + 3][lrow] = b4.w;
        __syncthreads();
        #pragma unroll
        for (int kk = 0; kk < 16; kk++) {
            float4 av = *(const float4*)&As[kk][ty * 4];
            float4 bv = *(const float4*)&Bs[kk][tx * 4];
            acc[0][0] = fmaf(av.x, bv.x, acc[0][0]); acc[0][1] = fmaf(av.x, bv.y, acc[0][1]);
            acc[0][2] = fmaf(av.x, bv.z, acc[0][2]); acc[0][3] = fmaf(av.x, bv.w, acc[0][3]);
            acc[1][0] = fmaf(av.y, bv.x, acc[1][0]); acc[1][1] = fmaf(av.y, bv.y, acc[1][1]);
            acc[1][2] = fmaf(av.y, bv.z, acc[1][2]); acc[1][3] = fmaf(av.y, bv.w, acc[1][3]);
            acc[2][0] = fmaf(av.z, bv.x, acc[2][0]); acc[2][1] = fmaf(av.z, bv.y, acc[2][1]);
            acc[2][2] = fmaf(av.z, bv.z, acc[2][2]); acc[2][3] = fmaf(av.z, bv.w, acc[2][3]);
            acc[3][0] = fmaf(av.w, bv.x, acc[3][0]); acc[3][1] = fmaf(av.w, bv.y, acc[3][1]);
            acc[3][2] = fmaf(av.w, bv.z, acc[3][2]); acc[3][3] = fmaf(av.w, bv.w, acc[3][3]);
        }
        __syncthreads();
    }
    #pragma unroll
    for (int im = 0; im < 4; im++) {
        int m = m0 + ty * 4 + im;
        int n = n0 + tx * 4;
        float4 o;
        o.x = acc[im][0] + bias[n + 0];
        o.y = acc[im][1] + bias[n + 1];
        o.z = acc[im][2] + bias[n + 2];
        o.w = acc[im][3] + bias[n + 3];
        *(float4*)&Cc[(size_t)m * J_ + n] = o;
    }
}

// Sequential recurrence. One block per batch, thread = neuron (4 branch rows).
__global__ __launch_bounds__(512) void rnn_loop(const float* __restrict__ W2T,
                                                const float* __restrict__ proj_in,
                                                const float* __restrict__ gating,
                                                const float* __restrict__ tau_m,
                                                const float* __restrict__ tau_n,
                                                const float* __restrict__ w_ro,
                                                const float* __restrict__ b_ro,
                                                const float* __restrict__ tau_m_ro,
                                                float* __restrict__ out) {
    int b   = blockIdx.x;   // 0..31
    int tid = threadIdx.x;  // 0..511 = neuron id
    __shared__ float spkLDS[R_];
    __shared__ float red[160];

    float alpha = 1.f / (1.f + expf(-tau_m[tid]));
    float oma   = 1.f - alpha;
    float beta[4], omb[4], d_in[4];
    #pragma unroll
    for (int q = 0; q < 4; q++) {
        beta[q] = 1.f / (1.f + expf(-tau_n[tid * 4 + q]));
        omb[q]  = 1.f - beta[q];
        d_in[q] = 0.f;
    }
    float mem = 0.f, spk = 0.f;
    float alpha_o = 0.f, mem_o = 0.f, spk_o = 0.f, bro = 0.f;
    if (tid < C_) {
        alpha_o = 1.f / (1.f + expf(-tau_m_ro[tid]));
        bro = b_ro[tid];
    }
    spkLDS[tid] = 0.f;
    __syncthreads();

    const float* proj_b = proj_in + (size_t)b * T_ * J_;
    const float* gat_b  = gating  + (size_t)b * T_ * R_;
    float* out_mem = out + (size_t)b * C_ * T_;                        // [C][T]
    float* out_spk = out + (size_t)B_ * C_ * T_ + (size_t)b * R_ * T_; // [R][T]
    int c  = tid >> 4;   // readout partial: output class
    int ri = tid & 15;   // readout partial: 32-chunk index

    for (int t = 0; t < T_; t++) {
        // ---- recurrent projection from previous spikes: a[q] = sum_r spk[r]*W2T[r][4*tid+q]
        float a0 = 0.f, a1 = 0.f, a2 = 0.f, a3 = 0.f;
        #pragma unroll 2
        for (int r0 = 0; r0 < R_; r0 += 4) {
            float4 s4 = *(const float4*)&spkLDS[r0];
            float ss[4] = { s4.x, s4.y, s4.z, s4.w };
            #pragma unroll
            for (int q = 0; q < 4; q++) {
                float4 w = *(const float4*)&W2T[(size_t)(r0 + q) * J_ + 4 * tid];
                a0 = fmaf(ss[q], w.x, a0);
                a1 = fmaf(ss[q], w.y, a1);
                a2 = fmaf(ss[q], w.z, a2);
                a3 = fmaf(ss[q], w.w, a3);
            }
        }
        float4 pj = *(const float4*)&proj_b[(size_t)t * J_ + 4 * tid];
        float g = gat_b[(size_t)t * R_ + tid];

        float dn0 = beta[0] * d_in[0] + omb[0] * (pj.x + a0);
        float dn1 = beta[1] * d_in[1] + omb[1] * (pj.y + a1);
        float dn2 = beta[2] * d_in[2] + omb[2] * (pj.z + a2);
        float dn3 = beta[3] * d_in[3] + omb[3] * (pj.w + a3);
        float l_in = dn0 + dn1 + dn2 + dn3;
        float mem_new = mem * alpha + oma * l_in - VTH * spk;
        float spk_new = (mem_new - VTH) > 0.f ? 1.f : 0.f;
        d_in[0] = g * dn0 + (1.f - g) * d_in[0];
        d_in[1] = g * dn1 + (1.f - g) * d_in[1];
        d_in[2] = g * dn2 + (1.f - g) * d_in[2];
        d_in[3] = g * dn3 + (1.f - g) * d_in[3];
        mem = g * mem_new + (1.f - g) * mem;
        spk = g * spk_new + (1.f - g) * spk;

        __syncthreads();                 // S1: everyone done reading old spikes
        spkLDS[tid] = spk;
        out_spk[(size_t)tid * T_ + t] = spk;
        __syncthreads();                 // S2: new spikes visible

        // ---- readout LIF
        if (tid < 160) {
            float p = 0.f;
            const float* wr = w_ro + (size_t)c * R_ + ri * 32;
            const float* sp = spkLDS + ri * 32;
            #pragma unroll
            for (int m = 0; m < 32; m++) p = fmaf(wr[m], sp[m], p);
            red[tid] = p;
        }
        __syncthreads();                 // S3: partials ready
        if (tid < C_) {
            float ro = bro;
            #pragma unroll
            for (int i2 = 0; i2 < 16; i2++) ro += red[tid * 16 + i2];
            float mo = mem_o * alpha_o + (1.f - alpha_o) * ro - VTH * spk_o;
            spk_o = (mo - VTH) > 0.f ? 1.f : 0.f;
            mem_o = mo;
            out_mem[(size_t)tid * T_ + t] = mo;
        }
    }
}

extern "C" void kernel_launch(void* const* d_in, const int* in_sizes, int n_in,
                              void* d_out, int out_size, void* d_ws, size_t ws_size,
                              hipStream_t stream) {
    const float* inp      = (const float*)d_in[0];
    const float* gat      = (const float*)d_in[1];
    const float* w_in     = (const float*)d_in[2];
    const float* b_in     = (const float*)d_in[3];
    const float* w_rnn    = (const float*)d_in[4];
    const float* b_rnn    = (const float*)d_in[5];
    const float* tau_m    = (const float*)d_in[6];
    const float* tau_n    = (const float*)d_in[7];
    const float* w_ro     = (const float*)d_in[8];
    const float* b_ro     = (const float*)d_in[9];
    const float* tau_m_ro = (const float*)d_in[10];
    const float* mask     = (const float*)d_in[11];

    float* ws   = (float*)d_ws;
    float* W1   = ws;                 // 1,048,576
    float* W2T  = ws + 1048576;       // 1,048,576
    float* cur  = ws + 2097152;       // 3,276,800
    float* proj = ws + 5373952;       // 13,107,200
    float* out  = (float*)d_out;

    prep_w1<<<4096, 256, 0, stream>>>(w_rnn, mask, W1);
    prep_w2t<<<dim3(32, 8), 256, 0, stream>>>(w_rnn, mask, W2T);
    currents_kernel<<<8192, 256, 0, stream>>>(inp, w_in, b_in, cur);
    gemm_proj<<<dim3(32, 100), 256, 0, stream>>>(cur, W1, b_rnn, proj);
    rnn_loop<<<32, 512, 0, stream>>>(W2T, proj, gat, tau_m, tau_n, w_ro, b_ro, tau_m_ro, out);
}